// Round 3
// baseline (27381.183 us; speedup 1.0000x reference)
//
#include <hip/hip_runtime.h>

// BiLSTM-CRF tagger. V=100000 E=300 H=512 C=40 T=4096. ALL I/O float32.
// Pipeline: GEMM Wx0{f,b} (emb gather fused) -> lstm phase A (layer0 f+b, 32 wgs/dir,
// flag-sync over MALL) -> GEMM Wx1{f,b} (concat-hist A) -> lstm phase B ->
// classifier+logsoftmax (writes d_out scores) -> viterbi fwd + backtrack (writes d_out tags).
// Full fp32 numerics: Viterbi argmax margins (~1e-2) cannot tolerate bf16-level noise.

typedef unsigned int u32;

#define TT 4096
#define HH 512
#define CC 40
#define NG 2048  // 4*H gate rows

__device__ __forceinline__ float sigm(float x) { return 1.0f / (1.0f + __expf(-x)); }
__device__ __forceinline__ float tanh_(float x) { return 1.0f - 2.0f / (__expf(2.0f * x) + 1.0f); }

__device__ __forceinline__ u32 ld_agent_u32(const u32* p) {
    return __hip_atomic_load((u32*)p, __ATOMIC_RELAXED, __HIP_MEMORY_SCOPE_AGENT);
}
__device__ __forceinline__ void st_agent_u32(u32* p, u32 v) {
    __hip_atomic_store(p, v, __ATOMIC_RELAXED, __HIP_MEMORY_SCOPE_AGENT);
}
__device__ __forceinline__ float ld_agent_f32(const float* p) {
    return __uint_as_float(ld_agent_u32((const u32*)p));
}
__device__ __forceinline__ void st_agent_f32(float* p, float v) {
    st_agent_u32((u32*)p, __float_as_uint(v));
}

// ---------------- f32 GEMM: C[M,N] = A @ W^T + bias ----------------
// A row m: xidx ? emb[xidx[m]] (K cols)  :  concat(A0[m](Ksplit), A1[m](K-Ksplit)).
// 64x64 tile / 256 threads / 4x4 outputs per thread. LDS transposed tiles [k][row].
__global__ __launch_bounds__(256, 2) void gemm_f32_k(const float* __restrict__ A0,
                                                     const float* __restrict__ A1,
                                                     const int* __restrict__ xidx,
                                                     const float* __restrict__ W,
                                                     const float* __restrict__ bias,
                                                     float* __restrict__ C,
                                                     int M, int N, int K, int Ksplit) {
    __shared__ float sA[32][66];
    __shared__ float sW[32][66];
    int tid = threadIdx.x;
    int bn = blockIdx.x, bm = blockIdx.y;
    int tx = tid & 15, ty = tid >> 4;
    int srow = tid >> 2, skk = (tid & 3) * 8;

    int am = bm * 64 + srow;
    const float* arow0;
    const float* arow1 = nullptr;
    if (xidx) {
        arow0 = A0 + (size_t)xidx[am] * K;
    } else {
        arow0 = A0 + (size_t)am * Ksplit;
        arow1 = A1 + (size_t)am * Ksplit;
    }
    const float* wrow = W + (size_t)(bn * 64 + srow) * K;

    float acc[4][4] = {};

    for (int kc = 0; kc < K; kc += 32) {
        float av[8], wv[8];
        if (kc + 32 <= K) {
#pragma unroll
            for (int j = 0; j < 8; j++) {
                int k = kc + skk + j;
                av[j] = (xidx || k < Ksplit) ? arow0[k] : arow1[k - Ksplit];
                wv[j] = wrow[k];
            }
        } else {
#pragma unroll
            for (int j = 0; j < 8; j++) {
                int k = kc + skk + j;
                bool ok = k < K;
                av[j] = (ok ? ((xidx || k < Ksplit) ? arow0[k] : arow1[k - Ksplit]) : 0.f);
                wv[j] = ok ? wrow[k] : 0.f;
            }
        }
        __syncthreads();
#pragma unroll
        for (int j = 0; j < 8; j++) {
            sA[skk + j][srow] = av[j];
            sW[skk + j][srow] = wv[j];
        }
        __syncthreads();
#pragma unroll
        for (int k = 0; k < 32; k++) {
            float4 a4 = *(const float4*)&sA[k][ty * 4];
            float4 w4 = *(const float4*)&sW[k][tx * 4];
            acc[0][0] += a4.x * w4.x; acc[0][1] += a4.x * w4.y; acc[0][2] += a4.x * w4.z; acc[0][3] += a4.x * w4.w;
            acc[1][0] += a4.y * w4.x; acc[1][1] += a4.y * w4.y; acc[1][2] += a4.y * w4.z; acc[1][3] += a4.y * w4.w;
            acc[2][0] += a4.z * w4.x; acc[2][1] += a4.z * w4.y; acc[2][2] += a4.z * w4.z; acc[2][3] += a4.z * w4.w;
            acc[3][0] += a4.w * w4.x; acc[3][1] += a4.w * w4.y; acc[3][2] += a4.w * w4.z; acc[3][3] += a4.w * w4.w;
        }
    }

    int gm = bm * 64 + ty * 4;
    int gn = bn * 64 + tx * 4;
    float4 b4 = *(const float4*)&bias[gn];
#pragma unroll
    for (int mi = 0; mi < 4; mi++) {
        float4 o;
        o.x = acc[mi][0] + b4.x; o.y = acc[mi][1] + b4.y;
        o.z = acc[mi][2] + b4.z; o.w = acc[mi][3] + b4.w;
        *(float4*)&C[(size_t)(gm + mi) * N + gn] = o;
    }
}

// ---------------- LSTM recurrent phase ----------------
// 64 blocks x 256 threads: dir = blk>>5, wg = blk&31 owns h[wg*16..+16).
// Thread (r=tid>>2, seg=tid&3): gate row grow=(r>>4)*512 + wg*16 + (r&15), k in [seg*128,+128).
// Whh rows in fp32 registers (128 VGPR). Cross-wg h via agent-scope atomics; per-wg flags;
// ballot spin with abort cap. 64 blocks <= 256 CUs => co-resident.
__global__ __launch_bounds__(256, 1) void lstm_phase_k(const float* __restrict__ WxF,
                                                       const float* __restrict__ WxB,
                                                       const float* __restrict__ WhhF,
                                                       const float* __restrict__ WhhB,
                                                       float* __restrict__ histF,
                                                       float* __restrict__ histB,
                                                       u32* __restrict__ flags,  // [64]
                                                       u32* __restrict__ abortf) {
    const int wg = blockIdx.x & 31;
    const int dir = blockIdx.x >> 5;
    const int tid = threadIdx.x;
    const float* Wx = dir ? WxB : WxF;
    const float* Whh = dir ? WhhB : WhhF;
    float* hist = dir ? histB : histF;
    u32* myflags = flags + dir * 32;

    const int r = tid >> 2, seg = tid & 3;
    const int grow = (r >> 4) * 512 + wg * 16 + (r & 15);

    float w[128];
    {
        const float* wr = Whh + (size_t)grow * HH + seg * 128;
#pragma unroll
        for (int i = 0; i < 32; i++) {
            float4 v = *(const float4*)(wr + i * 4);
            w[i * 4 + 0] = v.x; w[i * 4 + 1] = v.y; w[i * 4 + 2] = v.z; w[i * 4 + 3] = v.w;
        }
    }

    __shared__ float lds_h[4 * 132];  // 4 segments, stride 132: conflict-free reads
    __shared__ float lds_g[64];
    float c_state = 0.f;

    for (int s = 0; s < TT; ++s) {
        const int t = dir ? (TT - 1 - s) : s;
        float wxv = 0.f;
        if (seg == 0) wxv = Wx[(size_t)t * NG + grow];

        if (s > 0) {
            if (tid < 64) {
                int it = 0;
                for (;;) {
                    u32 v = (tid < 32) ? ld_agent_u32(&myflags[tid]) : 0xFFFFFFFFu;
                    if (__ballot(v >= (u32)s) == ~0ull) break;
                    if (((++it) & 255) == 0) {
                        if (it > (1 << 20) || ld_agent_u32(abortf)) { st_agent_u32(abortf, 1u); break; }
                    }
                    __builtin_amdgcn_s_sleep(1);
                }
                __atomic_signal_fence(__ATOMIC_ACQ_REL);
            }
            __syncthreads();
            const int tprev = dir ? (t + 1) : (t - 1);
            const float* hp = hist + (size_t)tprev * HH;
            if (tid < 128) {
#pragma unroll
                for (int j = 0; j < 4; j++) {
                    int idx = tid * 4 + j;
                    float v = ld_agent_f32(hp + idx);
                    lds_h[(idx >> 7) * 132 + (idx & 127)] = v;
                }
            }
            __syncthreads();
            float acc = 0.f;
            const float4* hv4 = (const float4*)&lds_h[seg * 132];
#pragma unroll
            for (int i = 0; i < 32; i++) {
                float4 hv = hv4[i];
                acc += w[i * 4 + 0] * hv.x;
                acc += w[i * 4 + 1] * hv.y;
                acc += w[i * 4 + 2] * hv.z;
                acc += w[i * 4 + 3] * hv.w;
            }
            acc += __shfl_xor(acc, 1);
            acc += __shfl_xor(acc, 2);
            if (seg == 0) lds_g[r] = acc + wxv;
        } else {
            if (seg == 0) lds_g[r] = wxv;
        }
        __syncthreads();

        if (tid < 16) {
            float gi = lds_g[tid], gf = lds_g[16 + tid], gg = lds_g[32 + tid], go = lds_g[48 + tid];
            float iv = sigm(gi), fv = sigm(gf), gv = tanh_(gg), ov = sigm(go);
            c_state = fv * c_state + iv * gv;
            float h = ov * tanh_(c_state);
            st_agent_f32(&hist[(size_t)t * HH + wg * 16 + tid], h);
        }
        __builtin_amdgcn_s_waitcnt(0);  // drain h stores before flag store
        __syncthreads();
        if (tid == 0) st_agent_u32(&myflags[wg], (u32)(s + 1));
    }
}

// ---------------- classifier + log_softmax (writes scores to d_out) ----------------
__global__ __launch_bounds__(64, 4) void classifier_k(const float* __restrict__ histF,
                                                      const float* __restrict__ histB,
                                                      const float* __restrict__ Wc,
                                                      const float* __restrict__ bc,
                                                      float* __restrict__ outsc) {
    int t = blockIdx.x, lane = threadIdx.x;
    __shared__ float hrow[1024];
    const float4* hf4 = (const float4*)(histF + (size_t)t * HH);
    const float4* hb4 = (const float4*)(histB + (size_t)t * HH);
#pragma unroll
    for (int j = 0; j < 4; j++) {
        int idx4 = j * 64 + lane;  // 0..255 float4s
        float4 v = (idx4 < 128) ? hf4[idx4] : hb4[idx4 - 128];
        *(float4*)&hrow[idx4 * 4] = v;
    }
    __syncthreads();
    float o = 0.f;
    if (lane < CC) {
        o = bc[lane];
        const float4* wr = (const float4*)(Wc + (size_t)lane * 1024);
#pragma unroll 4
        for (int kk = 0; kk < 256; ++kk) {
            float4 w4 = wr[kk];
            float4 h4 = *(const float4*)&hrow[kk * 4];
            o += w4.x * h4.x + w4.y * h4.y + w4.z * h4.z + w4.w * h4.w;
        }
    }
    float m = (lane < CC) ? o : -1e30f;
#pragma unroll
    for (int d = 1; d < 64; d <<= 1) m = fmaxf(m, __shfl_xor(m, d));
    float ex = (lane < CC) ? __expf(o - m) : 0.f;
#pragma unroll
    for (int d = 1; d < 64; d <<= 1) ex += __shfl_xor(ex, d);
    float lse = m + __logf(ex);
    if (lane < CC) outsc[(size_t)t * CC + lane] = o - lse;
}

// ---------------- viterbi forward + backtrack (single wave) ----------------
__global__ __launch_bounds__(64) void viterbi_k(const float* __restrict__ em,
                                               const float* __restrict__ trans,
                                               const float* __restrict__ startv,
                                               const float* __restrict__ endv,
                                               unsigned char* __restrict__ bp,
                                               float* __restrict__ outtags) {
    int lane = threadIdx.x;
    __shared__ float sc[64];
    float tcol[CC];
#pragma unroll
    for (int p = 0; p < CC; p++) tcol[p] = 0.f;
    if (lane < CC) {
#pragma unroll
        for (int p = 0; p < CC; p++) tcol[p] = trans[p * CC + lane];  // trans[prev][next=lane]
    }
    float s = 0.f;
    if (lane < CC) s = startv[lane] + em[lane];

    for (int t = 1; t < TT; ++t) {
        if (lane < CC) sc[lane] = s;
        __syncthreads();
        float emv = (lane < CC) ? em[(size_t)t * CC + lane] : 0.f;
        float best = -1e30f;
        int bi = 0;
#pragma unroll
        for (int p = 0; p < CC; p++) {
            float cand = sc[p] + tcol[p];
            if (cand > best) { best = cand; bi = p; }  // strict > = first-max (jnp.argmax)
        }
        __syncthreads();
        if (lane < CC) {
            s = best + emv;
            bp[(size_t)t * CC + lane] = (unsigned char)bi;
        }
    }
    float fv = (lane < CC) ? (s + endv[lane]) : -1e30f;
    int fi = (lane < CC) ? lane : 63;
#pragma unroll
    for (int d = 1; d < 64; d <<= 1) {
        float ov = __shfl_xor(fv, d);
        int oi = __shfl_xor(fi, d);
        if (ov > fv || (ov == fv && oi < fi)) { fv = ov; fi = oi; }
    }
    __threadfence();   // bp stores (lanes 0..39) visible to lane 0's loads
    __syncthreads();
    if (lane == 0) {
        int cur = fi;
        outtags[TT - 1] = (float)cur;
        for (int t = TT - 2; t >= 0; --t) {
            cur = bp[(size_t)(t + 1) * CC + cur];
            outtags[t] = (float)cur;
        }
    }
}

extern "C" void kernel_launch(void* const* d_in, const int* in_sizes, int n_in,
                              void* d_out, int out_size, void* d_ws, size_t ws_size,
                              hipStream_t stream) {
    const int*   x     = (const int*)d_in[0];
    const float* emb   = (const float*)d_in[1];
    const float* Wih0f = (const float*)d_in[2];
    const float* Whh0f = (const float*)d_in[3];
    const float* b0f   = (const float*)d_in[4];
    const float* Wih0b = (const float*)d_in[5];
    const float* Whh0b = (const float*)d_in[6];
    const float* b0b   = (const float*)d_in[7];
    const float* Wih1f = (const float*)d_in[8];
    const float* Whh1f = (const float*)d_in[9];
    const float* b1f   = (const float*)d_in[10];
    const float* Wih1b = (const float*)d_in[11];
    const float* Whh1b = (const float*)d_in[12];
    const float* b1b   = (const float*)d_in[13];
    const float* Wc    = (const float*)d_in[14];
    const float* bc    = (const float*)d_in[15];
    const float* trans = (const float*)d_in[16];
    const float* startv= (const float*)d_in[17];
    const float* endv  = (const float*)d_in[18];

    char* ws = (char*)d_ws;
    // layout, total 84,148,224 B
    u32* flagsA = (u32*)(ws + 0);                          // 256 B
    u32* flagsB = (u32*)(ws + 256);                        // 256 B
    u32* abortf = (u32*)(ws + 512);
    unsigned char* bp = (unsigned char*)(ws + 1024);       // 4096*40 = 163,840
    float* WxF  = (float*)(ws + 262144);                   // 4096*2048*4 = 33,554,432
    float* WxB  = (float*)(ws + 33816576);                 // 33,554,432
    float* histF= (float*)(ws + 67371008);                 // 4096*512*4 = 8,388,608
    float* histB= (float*)(ws + 75759616);                 // 8,388,608 -> 84,148,224

    if (ws_size < (size_t)84148224) return;  // diagnostic: zero output => ws too small

    float* out_sc   = (float*)d_out;                 // 4096*40 scores
    float* out_tags = out_sc + (size_t)TT * CC;      // 4096 tags (as float)

    hipMemsetAsync(d_ws, 0, 1024, stream);
    // layer 0 input projections (emb gather fused into GEMM)
    gemm_f32_k<<<dim3(32, 64), 256, 0, stream>>>(emb, nullptr, x, Wih0f, b0f, WxF, TT, NG, 300, 300);
    gemm_f32_k<<<dim3(32, 64), 256, 0, stream>>>(emb, nullptr, x, Wih0b, b0b, WxB, TT, NG, 300, 300);
    lstm_phase_k<<<64, 256, 0, stream>>>(WxF, WxB, Whh0f, Whh0b, histF, histB, flagsA, abortf);
    // layer 1 input projections (A = concat(histF, histB))
    gemm_f32_k<<<dim3(32, 64), 256, 0, stream>>>(histF, histB, nullptr, Wih1f, b1f, WxF, TT, NG, 1024, 512);
    gemm_f32_k<<<dim3(32, 64), 256, 0, stream>>>(histF, histB, nullptr, Wih1b, b1b, WxB, TT, NG, 1024, 512);
    lstm_phase_k<<<64, 256, 0, stream>>>(WxF, WxB, Whh1f, Whh1b, histF, histB, flagsB, abortf);
    classifier_k<<<TT, 64, 0, stream>>>(histF, histB, Wc, bc, out_sc);
    viterbi_k<<<1, 64, 0, stream>>>(out_sc, trans, startv, endv, bp, out_tags);
}

// Round 4
// 20042.766 us; speedup vs baseline: 1.3661x; 1.3661x over previous
//
#include <hip/hip_runtime.h>

// BiLSTM-CRF tagger. V=100000 E=300 H=512 C=40 T=4096. ALL I/O float32.
// r4: LSTM sync rewritten — no flags, no store-ack. h words self-validate:
//   phase 0 (layer 0): stored plain; valid iff word != 0xAAAAAAAA (ws poison).
//   phase 1 (layer 1): stored with exponent bits flipped (^0x7F800000); |h|<=1 =>
//     stored exp >= 128, distinguishable from poison (exp 84) and stale layer-0
//     values (exp <= 127). Bit-exact decode.
// Pollers spin on the h words directly (u64 agent-scope loads) => critical path is
// ONE one-way MALL trip per step instead of 3 round trips.
// amdgpu_waves_per_eu(1,1) forces the 128 Whh weights into VGPRs (r3: compiler
// kept 84 VGPRs and refetched weights from L2 every step).

typedef unsigned int u32;
typedef unsigned long long u64;

#define TT 4096
#define HH 512
#define CC 40
#define NG 2048  // 4*H gate rows

__device__ __forceinline__ float sigm(float x) { return 1.0f / (1.0f + __expf(-x)); }
__device__ __forceinline__ float tanh_(float x) { return 1.0f - 2.0f / (__expf(2.0f * x) + 1.0f); }

__device__ __forceinline__ void st_agent_u32(u32* p, u32 v) {
    __hip_atomic_store(p, v, __ATOMIC_RELAXED, __HIP_MEMORY_SCOPE_AGENT);
}
__device__ __forceinline__ u64 ld_agent_u64(const u64* p) {
    return __hip_atomic_load((u64*)p, __ATOMIC_RELAXED, __HIP_MEMORY_SCOPE_AGENT);
}

// ---------------- f32 GEMM: C[M,N] = A @ W^T + bias ----------------
// A row m: xidx ? emb[xidx[m]] (K cols)  :  concat(A0[m](Ksplit), A1[m](K-Ksplit)).
// 64x64 tile / 256 threads / 4x4 outputs per thread. LDS transposed tiles [k][row].
__global__ __launch_bounds__(256, 2) void gemm_f32_k(const float* __restrict__ A0,
                                                     const float* __restrict__ A1,
                                                     const int* __restrict__ xidx,
                                                     const float* __restrict__ W,
                                                     const float* __restrict__ bias,
                                                     float* __restrict__ C,
                                                     int M, int N, int K, int Ksplit) {
    __shared__ float sA[32][66];
    __shared__ float sW[32][66];
    int tid = threadIdx.x;
    int bn = blockIdx.x, bm = blockIdx.y;
    int tx = tid & 15, ty = tid >> 4;
    int srow = tid >> 2, skk = (tid & 3) * 8;

    int am = bm * 64 + srow;
    const float* arow0;
    const float* arow1 = nullptr;
    if (xidx) {
        arow0 = A0 + (size_t)xidx[am] * K;
    } else {
        arow0 = A0 + (size_t)am * Ksplit;
        arow1 = A1 + (size_t)am * Ksplit;
    }
    const float* wrow = W + (size_t)(bn * 64 + srow) * K;

    float acc[4][4] = {};

    for (int kc = 0; kc < K; kc += 32) {
        float av[8], wv[8];
        if (kc + 32 <= K) {
#pragma unroll
            for (int j = 0; j < 8; j++) {
                int k = kc + skk + j;
                av[j] = (xidx || k < Ksplit) ? arow0[k] : arow1[k - Ksplit];
                wv[j] = wrow[k];
            }
        } else {
#pragma unroll
            for (int j = 0; j < 8; j++) {
                int k = kc + skk + j;
                bool ok = k < K;
                av[j] = (ok ? ((xidx || k < Ksplit) ? arow0[k] : arow1[k - Ksplit]) : 0.f);
                wv[j] = ok ? wrow[k] : 0.f;
            }
        }
        __syncthreads();
#pragma unroll
        for (int j = 0; j < 8; j++) {
            sA[skk + j][srow] = av[j];
            sW[skk + j][srow] = wv[j];
        }
        __syncthreads();
#pragma unroll
        for (int k = 0; k < 32; k++) {
            float4 a4 = *(const float4*)&sA[k][ty * 4];
            float4 w4 = *(const float4*)&sW[k][tx * 4];
            acc[0][0] += a4.x * w4.x; acc[0][1] += a4.x * w4.y; acc[0][2] += a4.x * w4.z; acc[0][3] += a4.x * w4.w;
            acc[1][0] += a4.y * w4.x; acc[1][1] += a4.y * w4.y; acc[1][2] += a4.y * w4.z; acc[1][3] += a4.y * w4.w;
            acc[2][0] += a4.z * w4.x; acc[2][1] += a4.z * w4.y; acc[2][2] += a4.z * w4.z; acc[2][3] += a4.z * w4.w;
            acc[3][0] += a4.w * w4.x; acc[3][1] += a4.w * w4.y; acc[3][2] += a4.w * w4.z; acc[3][3] += a4.w * w4.w;
        }
    }

    int gm = bm * 64 + ty * 4;
    int gn = bn * 64 + tx * 4;
    float4 b4 = *(const float4*)&bias[gn];
#pragma unroll
    for (int mi = 0; mi < 4; mi++) {
        float4 o;
        o.x = acc[mi][0] + b4.x; o.y = acc[mi][1] + b4.y;
        o.z = acc[mi][2] + b4.z; o.w = acc[mi][3] + b4.w;
        *(float4*)&C[(size_t)(gm + mi) * N + gn] = o;
    }
}

// ---------------- LSTM recurrent phase ----------------
// 64 blocks x 256 threads: dir = blk>>5, wg = blk&31 owns h[wg*16..+16).
// Thread (r=tid>>2, seg=tid&3): gate row grow=(r>>4)*512 + wg*16 + (r&15),
// k in [seg*128,+128). Whh row chunk in 128 VGPRs (waves_per_eu(1,1) => 512-reg
// budget, no remat). Sync: pollers (tid<248) spin on remote h u64s until both
// halves pass the per-phase validity predicate, decode, drop into LDS.
__global__ __attribute__((amdgpu_flat_work_group_size(256, 256), amdgpu_waves_per_eu(1, 1)))
void lstm_phase_k(const float* __restrict__ WxF,
                  const float* __restrict__ WxB,
                  const float* __restrict__ WhhF,
                  const float* __restrict__ WhhB,
                  float* __restrict__ histF,
                  float* __restrict__ histB,
                  int phase) {
    const int wg = blockIdx.x & 31;
    const int dir = blockIdx.x >> 5;
    const int tid = threadIdx.x;
    const float* Wx = dir ? WxB : WxF;
    const float* Whh = dir ? WhhB : WhhF;
    float* hist = dir ? histB : histF;
    const u32 ENC = phase ? 0x7F800000u : 0u;

    const int r = tid >> 2, seg = tid & 3;
    const int grow = (r >> 4) * 512 + wg * 16 + (r & 15);

    float w[128];
    {
        const float* wr = Whh + (size_t)grow * HH + seg * 128;
#pragma unroll
        for (int i = 0; i < 32; i++) {
            float4 v = *(const float4*)(wr + i * 4);
            w[i * 4 + 0] = v.x; w[i * 4 + 1] = v.y; w[i * 4 + 2] = v.z; w[i * 4 + 3] = v.w;
        }
    }

    // u64 index of the pair this thread polls (skips own wg's 8 pairs)
    const int j = (tid < 248) ? (tid + (tid >= wg * 8 ? 8 : 0)) : 0;

    __shared__ float lds_h[4 * 132];  // 4 seg-quarters, stride 132 (conflict-free f4 reads)
    __shared__ float lds_g[64];
    float c_state = 0.f;

    for (int s = 0; s < TT; ++s) {
        const int t = dir ? (TT - 1 - s) : s;
        float wxv = 0.f;
        if (seg == 0) wxv = Wx[(size_t)t * NG + grow];  // plain cached load

        if (s > 0) {
            const int tprev = dir ? (t + 1) : (t - 1);
            if (tid < 248) {
                const u64* p = (const u64*)(hist + (size_t)tprev * HH) + j;
                u64 v;
                int it = 0;
                for (;;) {
                    v = ld_agent_u64(p);
                    u32 lo = (u32)v, hi = (u32)(v >> 32);
                    bool ok = phase
                        ? (((lo & 0x7F800000u) >= 0x40000000u) && ((hi & 0x7F800000u) >= 0x40000000u))
                        : ((lo != 0xAAAAAAAAu) && (hi != 0xAAAAAAAAu));
                    if (ok || ++it > (1 << 20)) break;  // cap: never hang
                }
                u32 lo = (u32)v ^ ENC, hi = (u32)(v >> 32) ^ ENC;
                int idx = j * 2;
                lds_h[(idx >> 7) * 132 + (idx & 127)] = __uint_as_float(lo);
                lds_h[((idx + 1) >> 7) * 132 + ((idx + 1) & 127)] = __uint_as_float(hi);
            }
            __syncthreads();
            float acc = 0.f;
            const float4* hv4 = (const float4*)&lds_h[seg * 132];
#pragma unroll
            for (int i = 0; i < 32; i++) {
                float4 hv = hv4[i];
                acc += w[i * 4 + 0] * hv.x;
                acc += w[i * 4 + 1] * hv.y;
                acc += w[i * 4 + 2] * hv.z;
                acc += w[i * 4 + 3] * hv.w;
            }
            acc += __shfl_xor(acc, 1);
            acc += __shfl_xor(acc, 2);
            if (seg == 0) lds_g[r] = acc + wxv;
        } else {
            if (seg == 0) lds_g[r] = wxv;
        }
        __syncthreads();

        if (tid < 16) {
            float gi = lds_g[tid], gf = lds_g[16 + tid], gg = lds_g[32 + tid], go = lds_g[48 + tid];
            float iv = sigm(gi), fv = sigm(gf), gv = tanh_(gg), ov = sigm(go);
            c_state = fv * c_state + iv * gv;
            float h = ov * tanh_(c_state);
            int hidx = wg * 16 + tid;
            lds_h[(hidx >> 7) * 132 + (hidx & 127)] = h;  // own slice for next step's dot
            st_agent_u32((u32*)&hist[(size_t)t * HH + hidx], __float_as_uint(h) ^ ENC);
        }
        // no end barrier needed: pollers only touch remote LDS slots; lds_g next
        // write happens after the next poll barrier, which waits for tid<16.
    }
}

// ---------------- classifier + log_softmax (writes scores to d_out) ----------------
// hist holds phase-1 encoding: decode = xor 0x7F800000 per word.
__global__ __launch_bounds__(64, 4) void classifier_k(const float* __restrict__ histF,
                                                      const float* __restrict__ histB,
                                                      const float* __restrict__ Wc,
                                                      const float* __restrict__ bc,
                                                      float* __restrict__ outsc) {
    int t = blockIdx.x, lane = threadIdx.x;
    __shared__ float hrow[1024];
    const uint4* hf4 = (const uint4*)(histF + (size_t)t * HH);
    const uint4* hb4 = (const uint4*)(histB + (size_t)t * HH);
#pragma unroll
    for (int jj = 0; jj < 4; jj++) {
        int idx4 = jj * 64 + lane;  // 0..255 uint4s
        uint4 u = (idx4 < 128) ? hf4[idx4] : hb4[idx4 - 128];
        u.x ^= 0x7F800000u; u.y ^= 0x7F800000u; u.z ^= 0x7F800000u; u.w ^= 0x7F800000u;
        float4 v;
        v.x = __uint_as_float(u.x); v.y = __uint_as_float(u.y);
        v.z = __uint_as_float(u.z); v.w = __uint_as_float(u.w);
        *(float4*)&hrow[idx4 * 4] = v;
    }
    __syncthreads();
    float o = 0.f;
    if (lane < CC) {
        o = bc[lane];
        const float4* wr = (const float4*)(Wc + (size_t)lane * 1024);
#pragma unroll 4
        for (int kk = 0; kk < 256; ++kk) {
            float4 w4 = wr[kk];
            float4 h4 = *(const float4*)&hrow[kk * 4];
            o += w4.x * h4.x + w4.y * h4.y + w4.z * h4.z + w4.w * h4.w;
        }
    }
    float m = (lane < CC) ? o : -1e30f;
#pragma unroll
    for (int d = 1; d < 64; d <<= 1) m = fmaxf(m, __shfl_xor(m, d));
    float ex = (lane < CC) ? __expf(o - m) : 0.f;
#pragma unroll
    for (int d = 1; d < 64; d <<= 1) ex += __shfl_xor(ex, d);
    float lse = m + __logf(ex);
    if (lane < CC) outsc[(size_t)t * CC + lane] = o - lse;
}

// ---------------- viterbi forward + backtrack (single wave) ----------------
__global__ __launch_bounds__(64) void viterbi_k(const float* __restrict__ em,
                                               const float* __restrict__ trans,
                                               const float* __restrict__ startv,
                                               const float* __restrict__ endv,
                                               unsigned char* __restrict__ bp,
                                               float* __restrict__ outtags) {
    int lane = threadIdx.x;
    __shared__ float sc[64];
    float tcol[CC];
#pragma unroll
    for (int p = 0; p < CC; p++) tcol[p] = 0.f;
    if (lane < CC) {
#pragma unroll
        for (int p = 0; p < CC; p++) tcol[p] = trans[p * CC + lane];  // trans[prev][next=lane]
    }
    float s = 0.f;
    if (lane < CC) s = startv[lane] + em[lane];

    for (int t = 1; t < TT; ++t) {
        if (lane < CC) sc[lane] = s;
        __syncthreads();
        float emv = (lane < CC) ? em[(size_t)t * CC + lane] : 0.f;
        float best = -1e30f;
        int bi = 0;
#pragma unroll
        for (int p = 0; p < CC; p++) {
            float cand = sc[p] + tcol[p];
            if (cand > best) { best = cand; bi = p; }  // strict > = first-max (jnp.argmax)
        }
        __syncthreads();
        if (lane < CC) {
            s = best + emv;
            bp[(size_t)t * CC + lane] = (unsigned char)bi;
        }
    }
    float fv = (lane < CC) ? (s + endv[lane]) : -1e30f;
    int fi = (lane < CC) ? lane : 63;
#pragma unroll
    for (int d = 1; d < 64; d <<= 1) {
        float ov = __shfl_xor(fv, d);
        int oi = __shfl_xor(fi, d);
        if (ov > fv || (ov == fv && oi < fi)) { fv = ov; fi = oi; }
    }
    __threadfence();   // bp stores (lanes 0..39) visible to lane 0's loads
    __syncthreads();
    if (lane == 0) {
        int cur = fi;
        outtags[TT - 1] = (float)cur;
        for (int t = TT - 2; t >= 0; --t) {
            cur = bp[(size_t)(t + 1) * CC + cur];
            outtags[t] = (float)cur;
        }
    }
}

extern "C" void kernel_launch(void* const* d_in, const int* in_sizes, int n_in,
                              void* d_out, int out_size, void* d_ws, size_t ws_size,
                              hipStream_t stream) {
    const int*   x     = (const int*)d_in[0];
    const float* emb   = (const float*)d_in[1];
    const float* Wih0f = (const float*)d_in[2];
    const float* Whh0f = (const float*)d_in[3];
    const float* b0f   = (const float*)d_in[4];
    const float* Wih0b = (const float*)d_in[5];
    const float* Whh0b = (const float*)d_in[6];
    const float* b0b   = (const float*)d_in[7];
    const float* Wih1f = (const float*)d_in[8];
    const float* Whh1f = (const float*)d_in[9];
    const float* b1f   = (const float*)d_in[10];
    const float* Wih1b = (const float*)d_in[11];
    const float* Whh1b = (const float*)d_in[12];
    const float* b1b   = (const float*)d_in[13];
    const float* Wc    = (const float*)d_in[14];
    const float* bc    = (const float*)d_in[15];
    const float* trans = (const float*)d_in[16];
    const float* startv= (const float*)d_in[17];
    const float* endv  = (const float*)d_in[18];

    char* ws = (char*)d_ws;
    // layout, total 84,148,224 B (first 256 KB region: bp + slack)
    unsigned char* bp = (unsigned char*)(ws + 1024);       // 4096*40 = 163,840
    float* WxF  = (float*)(ws + 262144);                   // 4096*2048*4 = 33,554,432
    float* WxB  = (float*)(ws + 33816576);                 // 33,554,432
    float* histF= (float*)(ws + 67371008);                 // 4096*512*4 = 8,388,608
    float* histB= (float*)(ws + 75759616);                 // 8,388,608 -> 84,148,224

    if (ws_size < (size_t)84148224) return;  // diagnostic: zero output => ws too small

    float* out_sc   = (float*)d_out;                 // 4096*40 scores
    float* out_tags = out_sc + (size_t)TT * CC;      // 4096 tags (as float)

    // layer 0 input projections (emb gather fused into GEMM)
    gemm_f32_k<<<dim3(32, 64), 256, 0, stream>>>(emb, nullptr, x, Wih0f, b0f, WxF, TT, NG, 300, 300);
    gemm_f32_k<<<dim3(32, 64), 256, 0, stream>>>(emb, nullptr, x, Wih0b, b0b, WxB, TT, NG, 300, 300);
    lstm_phase_k<<<64, 256, 0, stream>>>(WxF, WxB, Whh0f, Whh0b, histF, histB, 0);
    // layer 1 input projections (A = concat(histF, histB), plain layer-0 bits)
    gemm_f32_k<<<dim3(32, 64), 256, 0, stream>>>(histF, histB, nullptr, Wih1f, b1f, WxF, TT, NG, 1024, 512);
    gemm_f32_k<<<dim3(32, 64), 256, 0, stream>>>(histF, histB, nullptr, Wih1b, b1b, WxB, TT, NG, 1024, 512);
    lstm_phase_k<<<64, 256, 0, stream>>>(WxF, WxB, Whh1f, Whh1b, histF, histB, 1);
    classifier_k<<<TT, 64, 0, stream>>>(histF, histB, Wc, bc, out_sc);
    viterbi_k<<<1, 64, 0, stream>>>(out_sc, trans, startv, endv, bp, out_tags);
}

// Round 5
// 19446.506 us; speedup vs baseline: 1.4080x; 1.0307x over previous
//
#include <hip/hip_runtime.h>

// BiLSTM-CRF tagger. V=100000 E=300 H=512 C=40 T=4096. ALL I/O float32.
// r5: lstm reworked — 512 threads/block, 64 weights/thread (arch VGPRs only; r4's
// 128/thread under waves_per_eu(1,1) landed in AGPRs => v_accvgpr_read per MAC),
// 4 independent FMA accumulators, 16B pollers. Sync scheme unchanged (r4):
//   phase 0 h stored plain (valid iff != 0xAAAAAAAA poison);
//   phase 1 h stored with exponent flipped (^0x7F800000): |h|<=1 => stored exp>=128,
//   distinguishable from poison (exp 85) and stale layer-0 values (exp<=127).
// Viterbi: shfl-broadcast (no LDS barriers) + split max chain.

typedef unsigned int u32;
typedef unsigned long long u64;

#define TT 4096
#define HH 512
#define CC 40
#define NG 2048  // 4*H gate rows

__device__ __forceinline__ float sigm(float x) { return 1.0f / (1.0f + __expf(-x)); }
__device__ __forceinline__ float tanh_(float x) { return 1.0f - 2.0f / (__expf(2.0f * x) + 1.0f); }

__device__ __forceinline__ void st_agent_u32(u32* p, u32 v) {
    __hip_atomic_store(p, v, __ATOMIC_RELAXED, __HIP_MEMORY_SCOPE_AGENT);
}
__device__ __forceinline__ u64 ld_agent_u64(const u64* p) {
    return __hip_atomic_load((u64*)p, __ATOMIC_RELAXED, __HIP_MEMORY_SCOPE_AGENT);
}

// ---------------- f32 GEMM: C[M,N] = A @ W^T + bias ----------------
// A row m: xidx ? emb[xidx[m]] (K cols)  :  concat(A0[m](Ksplit), A1[m](K-Ksplit)).
// 64x64 tile / 256 threads / 4x4 outputs per thread. LDS transposed tiles [k][row].
__global__ __launch_bounds__(256, 2) void gemm_f32_k(const float* __restrict__ A0,
                                                     const float* __restrict__ A1,
                                                     const int* __restrict__ xidx,
                                                     const float* __restrict__ W,
                                                     const float* __restrict__ bias,
                                                     float* __restrict__ C,
                                                     int M, int N, int K, int Ksplit) {
    __shared__ float sA[32][66];
    __shared__ float sW[32][66];
    int tid = threadIdx.x;
    int bn = blockIdx.x, bm = blockIdx.y;
    int tx = tid & 15, ty = tid >> 4;
    int srow = tid >> 2, skk = (tid & 3) * 8;

    int am = bm * 64 + srow;
    const float* arow0;
    const float* arow1 = nullptr;
    if (xidx) {
        arow0 = A0 + (size_t)xidx[am] * K;
    } else {
        arow0 = A0 + (size_t)am * Ksplit;
        arow1 = A1 + (size_t)am * Ksplit;
    }
    const float* wrow = W + (size_t)(bn * 64 + srow) * K;

    float acc[4][4] = {};

    for (int kc = 0; kc < K; kc += 32) {
        float av[8], wv[8];
        if (kc + 32 <= K) {
#pragma unroll
            for (int j = 0; j < 8; j++) {
                int k = kc + skk + j;
                av[j] = (xidx || k < Ksplit) ? arow0[k] : arow1[k - Ksplit];
                wv[j] = wrow[k];
            }
        } else {
#pragma unroll
            for (int j = 0; j < 8; j++) {
                int k = kc + skk + j;
                bool ok = k < K;
                av[j] = (ok ? ((xidx || k < Ksplit) ? arow0[k] : arow1[k - Ksplit]) : 0.f);
                wv[j] = ok ? wrow[k] : 0.f;
            }
        }
        __syncthreads();
#pragma unroll
        for (int j = 0; j < 8; j++) {
            sA[skk + j][srow] = av[j];
            sW[skk + j][srow] = wv[j];
        }
        __syncthreads();
#pragma unroll
        for (int k = 0; k < 32; k++) {
            float4 a4 = *(const float4*)&sA[k][ty * 4];
            float4 w4 = *(const float4*)&sW[k][tx * 4];
            acc[0][0] += a4.x * w4.x; acc[0][1] += a4.x * w4.y; acc[0][2] += a4.x * w4.z; acc[0][3] += a4.x * w4.w;
            acc[1][0] += a4.y * w4.x; acc[1][1] += a4.y * w4.y; acc[1][2] += a4.y * w4.z; acc[1][3] += a4.y * w4.w;
            acc[2][0] += a4.z * w4.x; acc[2][1] += a4.z * w4.y; acc[2][2] += a4.z * w4.z; acc[2][3] += a4.z * w4.w;
            acc[3][0] += a4.w * w4.x; acc[3][1] += a4.w * w4.y; acc[3][2] += a4.w * w4.z; acc[3][3] += a4.w * w4.w;
        }
    }

    int gm = bm * 64 + ty * 4;
    int gn = bn * 64 + tx * 4;
    float4 b4 = *(const float4*)&bias[gn];
#pragma unroll
    for (int mi = 0; mi < 4; mi++) {
        float4 o;
        o.x = acc[mi][0] + b4.x; o.y = acc[mi][1] + b4.y;
        o.z = acc[mi][2] + b4.z; o.w = acc[mi][3] + b4.w;
        *(float4*)&C[(size_t)(gm + mi) * N + gn] = o;
    }
}

// ---------------- LSTM recurrent phase ----------------
// 64 blocks x 512 threads: dir = blk>>5, wg = blk&31 owns h[wg*16..+16).
// Thread (r=tid>>3 in [0,64), seg=tid&7): gate row grow=(r>>4)*512 + wg*16 + (r&15),
// k in [seg*64, +64). 64 Whh weights/thread in arch VGPRs. Pollers tid<124 spin on
// remote 16B h chunks (2 x u64 agent loads) until both u64s pass the phase validity
// predicate, decode, drop into LDS. tid<16 computes gates, stores h (agent scope)
// and writes own LDS slice.
__global__ __attribute__((amdgpu_flat_work_group_size(512, 512), amdgpu_waves_per_eu(2, 2)))
void lstm_phase_k(const float* __restrict__ WxF,
                  const float* __restrict__ WxB,
                  const float* __restrict__ WhhF,
                  const float* __restrict__ WhhB,
                  float* __restrict__ histF,
                  float* __restrict__ histB,
                  int phase) {
    const int wg = blockIdx.x & 31;
    const int dir = blockIdx.x >> 5;
    const int tid = threadIdx.x;
    const float* Wx = dir ? WxB : WxF;
    const float* Whh = dir ? WhhB : WhhF;
    float* hist = dir ? histB : histF;
    const u32 ENC = phase ? 0x7F800000u : 0u;

    const int r = tid >> 3, seg = tid & 7;
    const int grow = (r >> 4) * 512 + wg * 16 + (r & 15);

    float w[64];
    {
        const float* wr = Whh + (size_t)grow * HH + seg * 64;
#pragma unroll
        for (int i = 0; i < 16; i++) {
            float4 v = *(const float4*)(wr + i * 4);
            w[i * 4 + 0] = v.x; w[i * 4 + 1] = v.y; w[i * 4 + 2] = v.z; w[i * 4 + 3] = v.w;
        }
    }

    // uint4-chunk index this thread polls (skips own wg's 4 chunks)
    const int j = (tid < 124) ? (tid + (tid >= wg * 4 ? 4 : 0)) : 0;

    __shared__ float lds_h[8 * 68];  // 8 seg-chunks of 64, stride 68 (conflict-free f4 reads)
    __shared__ float lds_g[64];
    float c_state = 0.f;
    int capped = 0;

    for (int s = 0; s < TT; ++s) {
        const int t = dir ? (TT - 1 - s) : s;
        float wxv = 0.f;
        if (seg == 0) wxv = Wx[(size_t)t * NG + grow];  // plain cached load

        if (s > 0) {
            const int tprev = dir ? (t + 1) : (t - 1);
            if (tid < 124) {
                const u64* p = (const u64*)(hist + (size_t)tprev * HH) + j * 2;
                u64 v0, v1;
                if (!capped) {
                    int it = 0;
                    for (;;) {
                        v0 = ld_agent_u64(p);
                        v1 = ld_agent_u64(p + 1);
                        u32 a = (u32)v0, b = (u32)(v0 >> 32), c = (u32)v1, d = (u32)(v1 >> 32);
                        bool ok = phase
                            ? (((a & 0x7F800000u) >= 0x40000000u) && ((b & 0x7F800000u) >= 0x40000000u) &&
                               ((c & 0x7F800000u) >= 0x40000000u) && ((d & 0x7F800000u) >= 0x40000000u))
                            : ((a != 0xAAAAAAAAu) && (b != 0xAAAAAAAAu) &&
                               (c != 0xAAAAAAAAu) && (d != 0xAAAAAAAAu));
                        if (ok) break;
                        if (++it > (1 << 19)) { capped = 1; break; }  // sticky: never hang
                    }
                } else {
                    v0 = ld_agent_u64(p);
                    v1 = ld_agent_u64(p + 1);
                }
                float4 hv;
                hv.x = __uint_as_float((u32)v0 ^ ENC);
                hv.y = __uint_as_float((u32)(v0 >> 32) ^ ENC);
                hv.z = __uint_as_float((u32)v1 ^ ENC);
                hv.w = __uint_as_float((u32)(v1 >> 32) ^ ENC);
                *(float4*)&lds_h[(j >> 4) * 68 + ((j * 4) & 63)] = hv;
            }
            __syncthreads();
            float a0 = 0.f, a1 = 0.f, a2 = 0.f, a3 = 0.f;
            const float4* hv4 = (const float4*)&lds_h[seg * 68];
#pragma unroll
            for (int i = 0; i < 16; i++) {
                float4 hv = hv4[i];
                a0 += w[i * 4 + 0] * hv.x;
                a1 += w[i * 4 + 1] * hv.y;
                a2 += w[i * 4 + 2] * hv.z;
                a3 += w[i * 4 + 3] * hv.w;
            }
            float acc = (a0 + a1) + (a2 + a3);
            acc += __shfl_xor(acc, 1);
            acc += __shfl_xor(acc, 2);
            acc += __shfl_xor(acc, 4);
            if (seg == 0) lds_g[r] = acc + wxv;
        } else {
            if (seg == 0) lds_g[r] = wxv;
        }
        __syncthreads();

        if (tid < 16) {
            float gi = lds_g[tid], gf = lds_g[16 + tid], gg = lds_g[32 + tid], go = lds_g[48 + tid];
            float iv = sigm(gi), fv = sigm(gf), gv = tanh_(gg), ov = sigm(go);
            c_state = fv * c_state + iv * gv;
            float h = ov * tanh_(c_state);
            int hidx = wg * 16 + tid;
            lds_h[(hidx >> 6) * 68 + (hidx & 63)] = h;  // own slice for next step's dot
            st_agent_u32((u32*)&hist[(size_t)t * HH + hidx], __float_as_uint(h) ^ ENC);
        }
        // no end barrier: remote LDS slices are dead until the next poll barrier,
        // and lds_g is rewritten only after that barrier (which waits for tid<16).
    }
}

// ---------------- classifier + log_softmax (writes scores to d_out) ----------------
// hist holds phase-1 encoding: decode = xor 0x7F800000 per word.
__global__ __launch_bounds__(64, 4) void classifier_k(const float* __restrict__ histF,
                                                      const float* __restrict__ histB,
                                                      const float* __restrict__ Wc,
                                                      const float* __restrict__ bc,
                                                      float* __restrict__ outsc) {
    int t = blockIdx.x, lane = threadIdx.x;
    __shared__ float hrow[1024];
    const uint4* hf4 = (const uint4*)(histF + (size_t)t * HH);
    const uint4* hb4 = (const uint4*)(histB + (size_t)t * HH);
#pragma unroll
    for (int jj = 0; jj < 4; jj++) {
        int idx4 = jj * 64 + lane;  // 0..255 uint4s
        uint4 u = (idx4 < 128) ? hf4[idx4] : hb4[idx4 - 128];
        u.x ^= 0x7F800000u; u.y ^= 0x7F800000u; u.z ^= 0x7F800000u; u.w ^= 0x7F800000u;
        float4 v;
        v.x = __uint_as_float(u.x); v.y = __uint_as_float(u.y);
        v.z = __uint_as_float(u.z); v.w = __uint_as_float(u.w);
        *(float4*)&hrow[idx4 * 4] = v;
    }
    __syncthreads();
    float o = 0.f;
    if (lane < CC) {
        o = bc[lane];
        const float4* wr = (const float4*)(Wc + (size_t)lane * 1024);
#pragma unroll 4
        for (int kk = 0; kk < 256; ++kk) {
            float4 w4 = wr[kk];
            float4 h4 = *(const float4*)&hrow[kk * 4];
            o += w4.x * h4.x + w4.y * h4.y + w4.z * h4.z + w4.w * h4.w;
        }
    }
    float m = (lane < CC) ? o : -1e30f;
#pragma unroll
    for (int d = 1; d < 64; d <<= 1) m = fmaxf(m, __shfl_xor(m, d));
    float ex = (lane < CC) ? __expf(o - m) : 0.f;
#pragma unroll
    for (int d = 1; d < 64; d <<= 1) ex += __shfl_xor(ex, d);
    float lse = m + __logf(ex);
    if (lane < CC) outsc[(size_t)t * CC + lane] = o - lse;
}

// ---------------- viterbi forward + backtrack (single wave, shfl broadcast) ----------------
__global__ __launch_bounds__(64) void viterbi_k(const float* __restrict__ em,
                                               const float* __restrict__ trans,
                                               const float* __restrict__ startv,
                                               const float* __restrict__ endv,
                                               unsigned char* __restrict__ bp,
                                               float* __restrict__ outtags) {
    int lane = threadIdx.x;
    float tcol[CC];
#pragma unroll
    for (int p = 0; p < CC; p++) tcol[p] = 0.f;
    if (lane < CC) {
#pragma unroll
        for (int p = 0; p < CC; p++) tcol[p] = trans[p * CC + lane];  // trans[prev][next=lane]
    }
    float s = (lane < CC) ? (startv[lane] + em[lane]) : 0.f;

    for (int t = 1; t < TT; ++t) {
        float emv = (lane < CC) ? em[(size_t)t * CC + lane] : 0.f;
        // two independent 20-deep max chains; combine keeps first-index semantics
        float b0 = -1e30f, b1 = -1e30f;
        int i0 = 0, i1 = 20;
#pragma unroll
        for (int p = 0; p < 20; p++) {
            float c0 = __shfl(s, p) + tcol[p];
            float c1 = __shfl(s, p + 20) + tcol[p + 20];
            if (c0 > b0) { b0 = c0; i0 = p; }       // strict > = first-max
            if (c1 > b1) { b1 = c1; i1 = p + 20; }
        }
        float best = b0; int bi = i0;
        if (b1 > b0) { best = b1; bi = i1; }        // tie -> lower-index chain 0
        s = best + emv;
        if (lane < CC) bp[(size_t)t * CC + lane] = (unsigned char)bi;
    }
    float fv = (lane < CC) ? (s + endv[lane]) : -1e30f;
    int fi = (lane < CC) ? lane : 63;
#pragma unroll
    for (int d = 1; d < 64; d <<= 1) {
        float ov = __shfl_xor(fv, d);
        int oi = __shfl_xor(fi, d);
        if (ov > fv || (ov == fv && oi < fi)) { fv = ov; fi = oi; }
    }
    __threadfence();   // bp stores (lanes 0..39) visible to lane 0's loads
    if (lane == 0) {
        int cur = fi;
        outtags[TT - 1] = (float)cur;
        for (int t = TT - 2; t >= 0; --t) {
            cur = bp[(size_t)(t + 1) * CC + cur];
            outtags[t] = (float)cur;
        }
    }
}

extern "C" void kernel_launch(void* const* d_in, const int* in_sizes, int n_in,
                              void* d_out, int out_size, void* d_ws, size_t ws_size,
                              hipStream_t stream) {
    const int*   x     = (const int*)d_in[0];
    const float* emb   = (const float*)d_in[1];
    const float* Wih0f = (const float*)d_in[2];
    const float* Whh0f = (const float*)d_in[3];
    const float* b0f   = (const float*)d_in[4];
    const float* Wih0b = (const float*)d_in[5];
    const float* Whh0b = (const float*)d_in[6];
    const float* b0b   = (const float*)d_in[7];
    const float* Wih1f = (const float*)d_in[8];
    const float* Whh1f = (const float*)d_in[9];
    const float* b1f   = (const float*)d_in[10];
    const float* Wih1b = (const float*)d_in[11];
    const float* Whh1b = (const float*)d_in[12];
    const float* b1b   = (const float*)d_in[13];
    const float* Wc    = (const float*)d_in[14];
    const float* bc    = (const float*)d_in[15];
    const float* trans = (const float*)d_in[16];
    const float* startv= (const float*)d_in[17];
    const float* endv  = (const float*)d_in[18];

    char* ws = (char*)d_ws;
    // layout, total 84,148,224 B
    unsigned char* bp = (unsigned char*)(ws + 1024);       // 4096*40 = 163,840
    float* WxF  = (float*)(ws + 262144);                   // 4096*2048*4 = 33,554,432
    float* WxB  = (float*)(ws + 33816576);                 // 33,554,432
    float* histF= (float*)(ws + 67371008);                 // 4096*512*4 = 8,388,608
    float* histB= (float*)(ws + 75759616);                 // 8,388,608 -> 84,148,224

    if (ws_size < (size_t)84148224) return;  // diagnostic: zero output => ws too small

    float* out_sc   = (float*)d_out;                 // 4096*40 scores
    float* out_tags = out_sc + (size_t)TT * CC;      // 4096 tags (as float)

    // layer 0 input projections (emb gather fused into GEMM)
    gemm_f32_k<<<dim3(32, 64), 256, 0, stream>>>(emb, nullptr, x, Wih0f, b0f, WxF, TT, NG, 300, 300);
    gemm_f32_k<<<dim3(32, 64), 256, 0, stream>>>(emb, nullptr, x, Wih0b, b0b, WxB, TT, NG, 300, 300);
    lstm_phase_k<<<64, 512, 0, stream>>>(WxF, WxB, Whh0f, Whh0b, histF, histB, 0);
    // layer 1 input projections (A = concat(histF, histB), plain layer-0 bits)
    gemm_f32_k<<<dim3(32, 64), 256, 0, stream>>>(histF, histB, nullptr, Wih1f, b1f, WxF, TT, NG, 1024, 512);
    gemm_f32_k<<<dim3(32, 64), 256, 0, stream>>>(histF, histB, nullptr, Wih1b, b1b, WxB, TT, NG, 1024, 512);
    lstm_phase_k<<<64, 512, 0, stream>>>(WxF, WxB, Whh1f, Whh1b, histF, histB, 1);
    classifier_k<<<TT, 64, 0, stream>>>(histF, histB, Wc, bc, out_sc);
    viterbi_k<<<1, 64, 0, stream>>>(out_sc, trans, startv, endv, bp, out_tags);
}

// Round 6
// 17662.947 us; speedup vs baseline: 1.5502x; 1.1010x over previous
//
#include <hip/hip_runtime.h>

// BiLSTM-CRF tagger. V=100000 E=300 H=512 C=40 T=4096. ALL I/O float32.
// r6: (a) lstm polls switched from atomic-u64 pairs to non-atomic 32B
//     global_load_dwordx4 sc0 sc1 (system-scope fresh, no MALL atomic-pipe
//     serialization), 62 pollers instead of 124;
//     (b) GEMM upgraded to 128x128 tile / 8x8 micro (was 64x64 / 4x4, ~11 TF).
// Sync scheme (r4/r5, proven): h words self-validate —
//   phase 0 stored plain (valid iff != 0xAAAAAAAA ws poison);
//   phase 1 stored with exponent flipped (^0x7F800000): |h|<1 => enc exp>=128,
//   distinguishable from poison (exp 85) and stale layer-0 values (exp<=127).

typedef unsigned int u32;
typedef unsigned long long u64;
typedef u32 u32x4 __attribute__((ext_vector_type(4)));

#define TT 4096
#define HH 512
#define CC 40
#define NG 2048  // 4*H gate rows

__device__ __forceinline__ float sigm(float x) { return 1.0f / (1.0f + __expf(-x)); }
__device__ __forceinline__ float tanh_(float x) { return 1.0f - 2.0f / (__expf(2.0f * x) + 1.0f); }

__device__ __forceinline__ void st_agent_u32(u32* p, u32 v) {
    __hip_atomic_store(p, v, __ATOMIC_RELAXED, __HIP_MEMORY_SCOPE_AGENT);
}

// 32B system-scope-fresh load (bypass L1+L2, read at MALL). Non-atomic: plain
// read path, no atomic-pipe serialization. waitcnt inside: compiler doesn't
// track asm load results.
__device__ __forceinline__ void ld_mall_b256(const float* p, u32x4& r0, u32x4& r1) {
    asm volatile(
        "global_load_dwordx4 %0, %2, off sc0 sc1\n\t"
        "global_load_dwordx4 %1, %2, off offset:16 sc0 sc1\n\t"
        "s_waitcnt vmcnt(0)"
        : "=&v"(r0), "=&v"(r1)
        : "v"(p)
        : "memory");
}

// ---------------- f32 GEMM: C[M,N] = A @ W^T + bias ----------------
// A row m: xidx ? emb[xidx[m]] (K cols) : concat(A0[m](Ksplit), A1[m](K-Ksplit)).
// 128x128 tile, 256 threads, 8x8 micro split as (4+4)x(4+4) halves 64 apart
// (keeps all LDS reads broadcast or 2-way). BK=8 panels, reg-prefetched staging.
__global__ __launch_bounds__(256, 2) void gemm_f32_k(const float* __restrict__ A0,
                                                     const float* __restrict__ A1,
                                                     const int* __restrict__ xidx,
                                                     const float* __restrict__ W,
                                                     const float* __restrict__ bias,
                                                     float* __restrict__ C,
                                                     int M, int N, int K, int Ksplit) {
    __shared__ float sA[8][132];
    __shared__ float sW[8][132];
    int tid = threadIdx.x;
    int bn = blockIdx.x, bm = blockIdx.y;
    int tx = tid & 15, ty = tid >> 4;
    int srow = tid >> 1, skh = (tid & 1) * 4;  // staging: row 0..127, k-half 0/4

    int am = bm * 128 + srow;
    const float* arow0;
    const float* arow1 = nullptr;
    if (xidx) {
        arow0 = A0 + (size_t)xidx[am] * K;
    } else {
        arow0 = A0 + (size_t)am * Ksplit;
        arow1 = A1 + (size_t)am * Ksplit;
    }
    const float* wrow = W + (size_t)(bn * 128 + srow) * K;

    float acc[2][2][4][4] = {};  // [mhalf][nhalf][mi][ni]

    for (int kc = 0; kc < K; kc += 8) {
        float4 av, wv;
        int k0 = kc + skh;
        if (kc + 8 <= K) {
            if (xidx || k0 + 4 <= Ksplit) av = *(const float4*)(arow0 + k0);
            else                          av = *(const float4*)(arow1 + (k0 - Ksplit));
            wv = *(const float4*)(wrow + k0);
        } else {  // K tail (K=300): per-element mask
            float a_[4], w_[4];
#pragma unroll
            for (int j = 0; j < 4; j++) {
                int k = k0 + j;
                bool ok = k < K;
                a_[j] = ok ? ((xidx || k < Ksplit) ? arow0[k] : arow1[k - Ksplit]) : 0.f;
                w_[j] = ok ? wrow[k] : 0.f;
            }
            av = make_float4(a_[0], a_[1], a_[2], a_[3]);
            wv = make_float4(w_[0], w_[1], w_[2], w_[3]);
        }
        __syncthreads();
        sA[skh + 0][srow] = av.x; sA[skh + 1][srow] = av.y;
        sA[skh + 2][srow] = av.z; sA[skh + 3][srow] = av.w;
        sW[skh + 0][srow] = wv.x; sW[skh + 1][srow] = wv.y;
        sW[skh + 2][srow] = wv.z; sW[skh + 3][srow] = wv.w;
        __syncthreads();
#pragma unroll
        for (int k = 0; k < 8; k++) {
            float4 a0 = *(const float4*)&sA[k][ty * 4];
            float4 a1 = *(const float4*)&sA[k][64 + ty * 4];
            float4 w0 = *(const float4*)&sW[k][tx * 4];
            float4 w1 = *(const float4*)&sW[k][64 + tx * 4];
            float am_[2][4] = {{a0.x, a0.y, a0.z, a0.w}, {a1.x, a1.y, a1.z, a1.w}};
            float wn_[2][4] = {{w0.x, w0.y, w0.z, w0.w}, {w1.x, w1.y, w1.z, w1.w}};
#pragma unroll
            for (int p = 0; p < 2; p++)
#pragma unroll
                for (int q = 0; q < 2; q++)
#pragma unroll
                    for (int mi = 0; mi < 4; mi++)
#pragma unroll
                        for (int ni = 0; ni < 4; ni++)
                            acc[p][q][mi][ni] += am_[p][mi] * wn_[q][ni];
        }
    }

#pragma unroll
    for (int q = 0; q < 2; q++) {
        int gn = bn * 128 + q * 64 + tx * 4;
        float4 b4 = *(const float4*)&bias[gn];
#pragma unroll
        for (int p = 0; p < 2; p++) {
            int gm = bm * 128 + p * 64 + ty * 4;
#pragma unroll
            for (int mi = 0; mi < 4; mi++) {
                float4 o;
                o.x = acc[p][q][mi][0] + b4.x; o.y = acc[p][q][mi][1] + b4.y;
                o.z = acc[p][q][mi][2] + b4.z; o.w = acc[p][q][mi][3] + b4.w;
                *(float4*)&C[(size_t)(gm + mi) * N + gn] = o;
            }
        }
    }
}

// ---------------- LSTM recurrent phase ----------------
// 64 blocks x 512 threads: dir = blk>>5, wg = blk&31 owns h[wg*16..+16).
// Thread (r=tid>>3, seg=tid&7): gate row grow=(r>>4)*512 + wg*16 + (r&15),
// k in [seg*64,+64). 64 Whh weights/thread in arch VGPRs. Pollers tid<62 spin on
// remote 32B h chunks (non-atomic sc0 sc1 dwordx4 pairs) until all 8 words pass
// the phase validity predicate, decode, drop into LDS. tid<16 computes gates,
// stores h (agent scope, one coalesced wave-instr) and writes own LDS slice.
__global__ __attribute__((amdgpu_flat_work_group_size(512, 512), amdgpu_waves_per_eu(2, 2)))
void lstm_phase_k(const float* __restrict__ WxF,
                  const float* __restrict__ WxB,
                  const float* __restrict__ WhhF,
                  const float* __restrict__ WhhB,
                  float* __restrict__ histF,
                  float* __restrict__ histB,
                  int phase) {
    const int wg = blockIdx.x & 31;
    const int dir = blockIdx.x >> 5;
    const int tid = threadIdx.x;
    const float* Wx = dir ? WxB : WxF;
    const float* Whh = dir ? WhhB : WhhF;
    float* hist = dir ? histB : histF;
    const u32 ENC = phase ? 0x7F800000u : 0u;

    const int r = tid >> 3, seg = tid & 7;
    const int grow = (r >> 4) * 512 + wg * 16 + (r & 15);

    float w[64];
    {
        const float* wr = Whh + (size_t)grow * HH + seg * 64;
#pragma unroll
        for (int i = 0; i < 16; i++) {
            float4 v = *(const float4*)(wr + i * 4);
            w[i * 4 + 0] = v.x; w[i * 4 + 1] = v.y; w[i * 4 + 2] = v.z; w[i * 4 + 3] = v.w;
        }
    }

    // 32B-chunk index this thread polls (64 chunks of 8 floats; skip own wg's 2)
    const int j = (tid < 62) ? (tid + (tid >= wg * 2 ? 2 : 0)) : 0;

    __shared__ float lds_h[8 * 68];  // 8 seg-chunks of 64, stride 68
    __shared__ float lds_g[64];
    float c_state = 0.f;
    int capped = 0;

    for (int s = 0; s < TT; ++s) {
        const int t = dir ? (TT - 1 - s) : s;
        float wxv = 0.f;
        if (seg == 0) wxv = Wx[(size_t)t * NG + grow];  // prefetch, hidden behind poll

        if (s > 0) {
            const int tprev = dir ? (t + 1) : (t - 1);
            if (tid < 62) {
                const float* p = hist + (size_t)tprev * HH + j * 8;
                u32x4 v0, v1;
                if (!capped) {
                    int it = 0;
                    for (;;) {
                        ld_mall_b256(p, v0, v1);
                        bool ok;
                        if (phase) {
                            ok = ((v0.x & 0x7F800000u) >= 0x40000000u) &&
                                 ((v0.y & 0x7F800000u) >= 0x40000000u) &&
                                 ((v0.z & 0x7F800000u) >= 0x40000000u) &&
                                 ((v0.w & 0x7F800000u) >= 0x40000000u) &&
                                 ((v1.x & 0x7F800000u) >= 0x40000000u) &&
                                 ((v1.y & 0x7F800000u) >= 0x40000000u) &&
                                 ((v1.z & 0x7F800000u) >= 0x40000000u) &&
                                 ((v1.w & 0x7F800000u) >= 0x40000000u);
                        } else {
                            ok = (v0.x != 0xAAAAAAAAu) && (v0.y != 0xAAAAAAAAu) &&
                                 (v0.z != 0xAAAAAAAAu) && (v0.w != 0xAAAAAAAAu) &&
                                 (v1.x != 0xAAAAAAAAu) && (v1.y != 0xAAAAAAAAu) &&
                                 (v1.z != 0xAAAAAAAAu) && (v1.w != 0xAAAAAAAAu);
                        }
                        if (ok) break;
                        if (++it > (1 << 18)) { capped = 1; break; }  // sticky: never hang
                    }
                } else {
                    ld_mall_b256(p, v0, v1);
                }
                float* dst = &lds_h[(j >> 3) * 68 + ((j & 7) * 8)];
                float4 f0, f1;
                f0.x = __uint_as_float(v0.x ^ ENC); f0.y = __uint_as_float(v0.y ^ ENC);
                f0.z = __uint_as_float(v0.z ^ ENC); f0.w = __uint_as_float(v0.w ^ ENC);
                f1.x = __uint_as_float(v1.x ^ ENC); f1.y = __uint_as_float(v1.y ^ ENC);
                f1.z = __uint_as_float(v1.z ^ ENC); f1.w = __uint_as_float(v1.w ^ ENC);
                *(float4*)dst = f0;
                *(float4*)(dst + 4) = f1;
            }
            __syncthreads();
            float a0 = 0.f, a1 = 0.f, a2 = 0.f, a3 = 0.f;
            const float4* hv4 = (const float4*)&lds_h[seg * 68];
#pragma unroll
            for (int i = 0; i < 16; i++) {
                float4 hv = hv4[i];
                a0 += w[i * 4 + 0] * hv.x;
                a1 += w[i * 4 + 1] * hv.y;
                a2 += w[i * 4 + 2] * hv.z;
                a3 += w[i * 4 + 3] * hv.w;
            }
            float acc = (a0 + a1) + (a2 + a3);
            acc += __shfl_xor(acc, 1);
            acc += __shfl_xor(acc, 2);
            acc += __shfl_xor(acc, 4);
            if (seg == 0) lds_g[r] = acc + wxv;
        } else {
            if (seg == 0) lds_g[r] = wxv;
        }
        __syncthreads();

        if (tid < 16) {
            float gi = lds_g[tid], gf = lds_g[16 + tid], gg = lds_g[32 + tid], go = lds_g[48 + tid];
            float iv = sigm(gi), fv = sigm(gf), gv = tanh_(gg), ov = sigm(go);
            c_state = fv * c_state + iv * gv;
            float h = ov * tanh_(c_state);
            int hidx = wg * 16 + tid;
            lds_h[(hidx >> 6) * 68 + (hidx & 63)] = h;  // own slice for next step's dot
            st_agent_u32((u32*)&hist[(size_t)t * HH + hidx], __float_as_uint(h) ^ ENC);
        }
        // no end barrier: remote LDS slices are dead until the next poll barrier,
        // and lds_g is rewritten only after that barrier (which waits for tid<16).
    }
}

// ---------------- classifier + log_softmax (writes scores to d_out) ----------------
// hist holds phase-1 encoding: decode = xor 0x7F800000 per word.
__global__ __launch_bounds__(64, 4) void classifier_k(const float* __restrict__ histF,
                                                      const float* __restrict__ histB,
                                                      const float* __restrict__ Wc,
                                                      const float* __restrict__ bc,
                                                      float* __restrict__ outsc) {
    int t = blockIdx.x, lane = threadIdx.x;
    __shared__ float hrow[1024];
    const uint4* hf4 = (const uint4*)(histF + (size_t)t * HH);
    const uint4* hb4 = (const uint4*)(histB + (size_t)t * HH);
#pragma unroll
    for (int jj = 0; jj < 4; jj++) {
        int idx4 = jj * 64 + lane;  // 0..255 uint4s
        uint4 u = (idx4 < 128) ? hf4[idx4] : hb4[idx4 - 128];
        u.x ^= 0x7F800000u; u.y ^= 0x7F800000u; u.z ^= 0x7F800000u; u.w ^= 0x7F800000u;
        float4 v;
        v.x = __uint_as_float(u.x); v.y = __uint_as_float(u.y);
        v.z = __uint_as_float(u.z); v.w = __uint_as_float(u.w);
        *(float4*)&hrow[idx4 * 4] = v;
    }
    __syncthreads();
    float o = 0.f;
    if (lane < CC) {
        o = bc[lane];
        const float4* wr = (const float4*)(Wc + (size_t)lane * 1024);
#pragma unroll 4
        for (int kk = 0; kk < 256; ++kk) {
            float4 w4 = wr[kk];
            float4 h4 = *(const float4*)&hrow[kk * 4];
            o += w4.x * h4.x + w4.y * h4.y + w4.z * h4.z + w4.w * h4.w;
        }
    }
    float m = (lane < CC) ? o : -1e30f;
#pragma unroll
    for (int d = 1; d < 64; d <<= 1) m = fmaxf(m, __shfl_xor(m, d));
    float ex = (lane < CC) ? __expf(o - m) : 0.f;
#pragma unroll
    for (int d = 1; d < 64; d <<= 1) ex += __shfl_xor(ex, d);
    float lse = m + __logf(ex);
    if (lane < CC) outsc[(size_t)t * CC + lane] = o - lse;
}

// ---------------- viterbi forward + backtrack (single wave, shfl broadcast) ----------------
__global__ __launch_bounds__(64) void viterbi_k(const float* __restrict__ em,
                                               const float* __restrict__ trans,
                                               const float* __restrict__ startv,
                                               const float* __restrict__ endv,
                                               unsigned char* __restrict__ bp,
                                               float* __restrict__ outtags) {
    int lane = threadIdx.x;
    float tcol[CC];
#pragma unroll
    for (int p = 0; p < CC; p++) tcol[p] = 0.f;
    if (lane < CC) {
#pragma unroll
        for (int p = 0; p < CC; p++) tcol[p] = trans[p * CC + lane];  // trans[prev][next=lane]
    }
    float s = (lane < CC) ? (startv[lane] + em[lane]) : 0.f;

    for (int t = 1; t < TT; ++t) {
        float emv = (lane < CC) ? em[(size_t)t * CC + lane] : 0.f;
        float b0 = -1e30f, b1 = -1e30f;
        int i0 = 0, i1 = 20;
#pragma unroll
        for (int p = 0; p < 20; p++) {
            float c0 = __shfl(s, p) + tcol[p];
            float c1 = __shfl(s, p + 20) + tcol[p + 20];
            if (c0 > b0) { b0 = c0; i0 = p; }       // strict > = first-max
            if (c1 > b1) { b1 = c1; i1 = p + 20; }
        }
        float best = b0; int bi = i0;
        if (b1 > b0) { best = b1; bi = i1; }        // tie -> lower-index chain 0
        s = best + emv;
        if (lane < CC) bp[(size_t)t * CC + lane] = (unsigned char)bi;
    }
    float fv = (lane < CC) ? (s + endv[lane]) : -1e30f;
    int fi = (lane < CC) ? lane : 63;
#pragma unroll
    for (int d = 1; d < 64; d <<= 1) {
        float ov = __shfl_xor(fv, d);
        int oi = __shfl_xor(fi, d);
        if (ov > fv || (ov == fv && oi < fi)) { fv = ov; fi = oi; }
    }
    __threadfence();   // bp stores (lanes 0..39) visible to lane 0's loads
    if (lane == 0) {
        int cur = fi;
        outtags[TT - 1] = (float)cur;
        for (int t = TT - 2; t >= 0; --t) {
            cur = bp[(size_t)(t + 1) * CC + cur];
            outtags[t] = (float)cur;
        }
    }
}

extern "C" void kernel_launch(void* const* d_in, const int* in_sizes, int n_in,
                              void* d_out, int out_size, void* d_ws, size_t ws_size,
                              hipStream_t stream) {
    const int*   x     = (const int*)d_in[0];
    const float* emb   = (const float*)d_in[1];
    const float* Wih0f = (const float*)d_in[2];
    const float* Whh0f = (const float*)d_in[3];
    const float* b0f   = (const float*)d_in[4];
    const float* Wih0b = (const float*)d_in[5];
    const float* Whh0b = (const float*)d_in[6];
    const float* b0b   = (const float*)d_in[7];
    const float* Wih1f = (const float*)d_in[8];
    const float* Whh1f = (const float*)d_in[9];
    const float* b1f   = (const float*)d_in[10];
    const float* Wih1b = (const float*)d_in[11];
    const float* Whh1b = (const float*)d_in[12];
    const float* b1b   = (const float*)d_in[13];
    const float* Wc    = (const float*)d_in[14];
    const float* bc    = (const float*)d_in[15];
    const float* trans = (const float*)d_in[16];
    const float* startv= (const float*)d_in[17];
    const float* endv  = (const float*)d_in[18];

    char* ws = (char*)d_ws;
    // layout, total 84,148,224 B
    unsigned char* bp = (unsigned char*)(ws + 1024);       // 4096*40 = 163,840
    float* WxF  = (float*)(ws + 262144);                   // 4096*2048*4 = 33,554,432
    float* WxB  = (float*)(ws + 33816576);                 // 33,554,432
    float* histF= (float*)(ws + 67371008);                 // 4096*512*4 = 8,388,608
    float* histB= (float*)(ws + 75759616);                 // 8,388,608 -> 84,148,224

    if (ws_size < (size_t)84148224) return;  // diagnostic: zero output => ws too small

    float* out_sc   = (float*)d_out;                 // 4096*40 scores
    float* out_tags = out_sc + (size_t)TT * CC;      // 4096 tags (as float)

    // layer 0 input projections (emb gather fused into GEMM)
    gemm_f32_k<<<dim3(16, 32), 256, 0, stream>>>(emb, nullptr, x, Wih0f, b0f, WxF, TT, NG, 300, 300);
    gemm_f32_k<<<dim3(16, 32), 256, 0, stream>>>(emb, nullptr, x, Wih0b, b0b, WxB, TT, NG, 300, 300);
    lstm_phase_k<<<64, 512, 0, stream>>>(WxF, WxB, Whh0f, Whh0b, histF, histB, 0);
    // layer 1 input projections (A = concat(histF, histB), plain layer-0 bits)
    gemm_f32_k<<<dim3(16, 32), 256, 0, stream>>>(histF, histB, nullptr, Wih1f, b1f, WxF, TT, NG, 1024, 512);
    gemm_f32_k<<<dim3(16, 32), 256, 0, stream>>>(histF, histB, nullptr, Wih1b, b1b, WxB, TT, NG, 1024, 512);
    lstm_phase_k<<<64, 512, 0, stream>>>(WxF, WxB, Whh1f, Whh1b, histF, histB, 1);
    classifier_k<<<TT, 64, 0, stream>>>(histF, histB, Wc, bc, out_sc);
    viterbi_k<<<1, 64, 0, stream>>>(out_sc, trans, startv, endv, bp, out_tags);
}